// Round 14
// baseline (103.720 us; speedup 1.0000x reference)
//
#include <hip/hip_runtime.h>
#include <hip/hip_bf16.h>
#include <stdint.h>

// Problem constants (B=16, N=512, D=768, H=6, Dh=128, layers=2)
#define BATCH 16
#define NSEQ  512
#define DMODEL 768
#define NHEAD 6
#define DHEAD 128
#define MROWS (BATCH * NSEQ)   // 8192
#define QBLK  32
#define KTILE 64

typedef __attribute__((ext_vector_type(8))) __bf16 bf16x8;
typedef __attribute__((ext_vector_type(4))) __bf16 bf16x4;
typedef __attribute__((ext_vector_type(4))) float  f32x4;
typedef __attribute__((ext_vector_type(4))) unsigned int u32x4;

#define GLD16(gp, lp) __builtin_amdgcn_global_load_lds( \
    (const __attribute__((address_space(1))) unsigned int*)(gp), \
    (__attribute__((address_space(3))) unsigned int*)(lp), 16, 0, 0)

// raw barrier (does NOT drain vmcnt -> global loads stay in flight)
#define BAR_PLAIN() do { asm volatile("" ::: "memory"); \
    __builtin_amdgcn_s_barrier(); asm volatile("" ::: "memory"); } while (0)
// barrier with LDS-op flush (producer side of ds_write -> cross-wave read)
#define BAR_LGKM() do { asm volatile("s_waitcnt lgkmcnt(0)" ::: "memory"); \
    __builtin_amdgcn_s_barrier(); asm volatile("" ::: "memory"); } while (0)

// ---------------- fp32 -> bf16 conversion (W only now; 0.6 MB) -----------
__global__ void cvt_bf16_kernel(const float* __restrict__ src,
                                __bf16* __restrict__ dst, int n4) {
    int i = blockIdx.x * blockDim.x + threadIdx.x;
    if (i < n4) {
        float4 v = reinterpret_cast<const float4*>(src)[i];
        bf16x4 o;
        o.x = (__bf16)v.x; o.y = (__bf16)v.y; o.z = (__bf16)v.z; o.w = (__bf16)v.w;
        reinterpret_cast<bf16x4*>(dst)[i] = o;
    }
}

// ---------------- bf16 MFMA GEMM (64x128 tile) + fused eq/ek epilogue -----
// AFP32=true: A staged as fp32 via the SAME GLD16 pipeline (2 GLD16/tile,
// source k pre-swizzled k^((row&7)<<2) so the swizzled b128 fragment reads
// are bank-spread); fp32->bf16 cvt at fragment read, under the MFMA shadow.
// Pipeline shape identical to the proven bf16 path (counted vmcnt, 2 bar/step).
template<bool AFP32>
__global__ __launch_bounds__(256) void gemm_bt(const void* __restrict__ Av,
                                               const __bf16* __restrict__ Bm,
                                               __bf16* __restrict__ C,
                                               const float* __restrict__ Wa,
                                               const float* __restrict__ pmask,
                                               float* __restrict__ eq_t,
                                               float* __restrict__ ek_t) {
    const __bf16* Ab = reinterpret_cast<const __bf16*>(Av);
    const float*  Af = reinterpret_cast<const float*>(Av);

    __shared__ __align__(16) __bf16 As[2][AFP32 ? 4096 : 2048];  // 16 KB : 8 KB total
    __shared__ __align__(16) __bf16 Bs[2][128 * 32];
    const int tid  = threadIdx.x;
    const int lane = tid & 63;
    const int wave = tid >> 6;
    const int wm = wave >> 1, wn = wave & 1;   // wave: 32m x 64n

    const int wg  = blockIdx.x;
    const int nid = (wg & 7) * 96 + (wg >> 3);  // 768 = 8*96
    const int bx  = nid % 6;
    const int by  = nid / 6;
    const int m0 = by * 64;
    const int n0 = bx * 128;

    f32x4 acc[2][4] = {};

    const int e0   = tid * 8;
    const int row0 = tid >> 2;
    const int k0i  = (tid & 3) * 8;

    const int lr = lane & 15;
    const int lg = lane >> 4;
    const int kb = lg * 8;

    auto STAGE = [&](int kt, int bufi) {
        if constexpr (AFP32) {
            #pragma unroll
            for (int i2 = 0; i2 < 2; i2++) {
                int tt  = tid + 256 * i2;
                int row = tt >> 3;                               // 0..63
                int k0s = ((tt & 7) * 4) ^ ((row & 7) << 2);     // pre-swizzled quad
                GLD16(Af + (size_t)(m0 + row) * DMODEL + kt + k0s,
                      reinterpret_cast<float*>(&As[bufi][0]) + tt * 4);
            }
        } else {
            GLD16(Ab + (size_t)(m0 + row0) * DMODEL + kt + k0i, &As[bufi][e0]);
        }
        GLD16(Bm + (size_t)(n0 + row0)      * DMODEL + kt + k0i, &Bs[bufi][e0]);
        GLD16(Bm + (size_t)(n0 + row0 + 64) * DMODEL + kt + k0i, &Bs[bufi][e0 + 2048]);
    };

    STAGE(0, 0);

    for (int t = 0; t < 24; t++) {
        const int buf = t & 1;
        if (t < 23) {
            STAGE((t + 1) * 32, buf ^ 1);
            if constexpr (AFP32) asm volatile("s_waitcnt vmcnt(4)" ::: "memory");
            else                 asm volatile("s_waitcnt vmcnt(3)" ::: "memory");
        } else {
            asm volatile("s_waitcnt vmcnt(0)" ::: "memory");
        }
        __builtin_amdgcn_s_barrier();
        asm volatile("" ::: "memory");

        bf16x8 af[2], bfv[4];
        if constexpr (AFP32) {
            const float* A32 = reinterpret_cast<const float*>(&As[buf][0]);
            const int sw = (lr & 7) << 2;
            #pragma unroll
            for (int i = 0; i < 2; i++) {
                int row = wm * 32 + i * 16 + lr;                 // row&7 == lr&7
                f32x4 lo = *reinterpret_cast<const f32x4*>(&A32[row * 32 + (kb ^ sw)]);
                f32x4 hi = *reinterpret_cast<const f32x4*>(&A32[row * 32 + ((kb + 4) ^ sw)]);
                #pragma unroll
                for (int j = 0; j < 4; j++) {
                    af[i][j]     = (__bf16)lo[j];
                    af[i][4 + j] = (__bf16)hi[j];
                }
            }
        } else {
            #pragma unroll
            for (int i = 0; i < 2; i++)
                af[i] = *reinterpret_cast<const bf16x8*>(&As[buf][(wm * 32 + i * 16 + lr) * 32 + kb]);
        }
        #pragma unroll
        for (int j = 0; j < 4; j++)
            bfv[j] = *reinterpret_cast<const bf16x8*>(&Bs[buf][(wn * 64 + j * 16 + lr) * 32 + kb]);
        #pragma unroll
        for (int i = 0; i < 2; i++)
            #pragma unroll
            for (int j = 0; j < 4; j++)
                acc[i][j] = __builtin_amdgcn_mfma_f32_16x16x32_bf16(af[i], bfv[j], acc[i][j], 0, 0, 0);

        BAR_PLAIN();
    }

    const int rg = lg * 4;
    #pragma unroll
    for (int i = 0; i < 2; i++) {
        #pragma unroll
        for (int j = 0; j < 4; j++) {
            #pragma unroll
            for (int r = 0; r < 4; r++) {
                int row = m0 + wm * 32 + i * 16 + rg + r;
                int col = n0 + wn * 64 + j * 16 + lr;
                C[(size_t)row * DMODEL + col] = (__bf16)acc[i][j][r];
            }
        }
    }

    // ---- fused sq/sk reduction -> eq = pm*e^{2sq}, ek = pm*e^{2sk} ----
    const int h = bx;
    float wqv[4], wkv[4];
    #pragma unroll
    for (int j = 0; j < 4; j++) {
        int d = wn * 64 + j * 16 + lr;
        wqv[j] = Wa[h * 256 + d];
        wkv[j] = Wa[h * 256 + 128 + d];
    }
    float* red = reinterpret_cast<float*>(&As[0][0]);
    #pragma unroll
    for (int i = 0; i < 2; i++) {
        #pragma unroll
        for (int r = 0; r < 4; r++) {
            float aq = 0.f, ak = 0.f;
            #pragma unroll
            for (int j = 0; j < 4; j++) {
                aq += acc[i][j][r] * wqv[j];
                ak += acc[i][j][r] * wkv[j];
            }
            #pragma unroll
            for (int off = 1; off < 16; off <<= 1) {
                aq += __shfl_xor(aq, off);
                ak += __shfl_xor(ak, off);
            }
            if (lr == 0) {
                int row = wm * 32 + i * 16 + rg + r;
                red[(0 * 64 + row) * 2 + wn] = aq;
                red[(1 * 64 + row) * 2 + wn] = ak;
            }
        }
    }
    __syncthreads();
    if (tid < 64) {
        int row = m0 + tid;
        float s = red[tid * 2] + red[tid * 2 + 1];
        eq_t[(size_t)h * MROWS + row] = (pmask[row] > 0.f) ? __expf(2.f * s) : 0.f;
    } else if (tid < 128) {
        int rl  = tid - 64;
        int row = m0 + rl;
        float s = red[(64 + rl) * 2] + red[(64 + rl) * 2 + 1];
        ek_t[(size_t)h * MROWS + row] = (pmask[row] > 0.f) ? __expf(2.f * s) : 0.f;
    }
}

// ---------------- fused score/softmax/MFMA-PV/tanh/residual ----------------
// grid 1536 XCD-chunked; block 256 (4 waves x 32 d-cols). QBLK=32, dbuf Vt,
// 64KB LDS, reads-before-writes tile order (R13 structure).
// LAYER=0: residual fp32 feature, output bf16.  LAYER=1: residual bf16, out fp32.
template<int LAYER>
__global__ __launch_bounds__(256) void attn_pv(const __bf16* __restrict__ QK,
                                               const float* __restrict__ eq_t,
                                               const float* __restrict__ ek_t,
                                               const float* __restrict__ resf,
                                               const __bf16* __restrict__ resb,
                                               float* __restrict__ outf,
                                               __bf16* __restrict__ outb) {
    const int wg  = blockIdx.x;
    const int nid = (wg & 7) * 192 + (wg >> 3);   // bijective: 1536 = 8*192
    const int qt = nid & 15;          // 16 q-tiles of 32
    const int hb = nid >> 4;          // 0..95
    const int h  = hb % NHEAD;
    const int b  = hb / NHEAD;
    const int q0 = qt * QBLK;

    __shared__ __align__(16) __bf16 w[QBLK][512];            // 32,768 B (swizzled cols)
    __shared__ __align__(16) __bf16 Vt[2][DHEAD * KTILE];    // 2 x 16,384 B
    const int tid  = threadIdx.x;
    const int lane = tid & 63;
    const int wave = tid >> 6;

    const int wd0 = wave * 32;
    const int lr  = lane & 15;
    const int lg  = lane >> 4;

    // ---- staging geometry; issue V tiles 0,1 EARLY ----
    const int sd0 = (tid & 15) * 8;
    const int sk0 = (tid >> 4) * 4;
    const __bf16* Vbase = QK + (size_t)b * NSEQ * DMODEL + (size_t)h * DHEAD + sd0;

    u32x4 A0, A1, A2, A3, B0, B1, B2, B3;
    #define LOADS(S0, S1, S2, S3, t) do { \
        const __bf16* p = Vbase + (size_t)((t) * KTILE + sk0) * DMODEL; \
        S0 = *reinterpret_cast<const u32x4*>(p); \
        S1 = *reinterpret_cast<const u32x4*>(p + DMODEL); \
        S2 = *reinterpret_cast<const u32x4*>(p + 2 * DMODEL); \
        S3 = *reinterpret_cast<const u32x4*>(p + 3 * DMODEL); \
    } while (0)
    #define WRITEV(S0, S1, S2, S3, bufi) do { \
        char* vtw = reinterpret_cast<char*>(&Vt[bufi][0]); \
        _Pragma("unroll") \
        for (int j = 0; j < 8; j++) { \
            int d = sd0 + j; \
            int swz = j ^ (tid & 7); \
            unsigned sel = (j & 1) ? 0x07060302u : 0x05040100u; \
            unsigned lo = __builtin_amdgcn_perm(S1[j >> 1], S0[j >> 1], sel); \
            unsigned hi = __builtin_amdgcn_perm(S3[j >> 1], S2[j >> 1], sel); \
            unsigned long long pk = (unsigned long long)lo | ((unsigned long long)hi << 32); \
            *reinterpret_cast<unsigned long long*>(vtw + d * 128 + ((sk0 ^ (swz << 3)) * 2)) = pk; \
        } \
    } while (0)

    LOADS(A0, A1, A2, A3, 0);          // latency hidden under phase 0/1
    LOADS(B0, B1, B2, B3, 1);

    // ---- early residual prefetch (compile-time source select) ----
    float res[2][4][2];
    #pragma unroll
    for (int qh = 0; qh < 2; qh++) {
        #pragma unroll
        for (int r = 0; r < 4; r++) {
            int ql = qh * 16 + lg * 4 + r;
            #pragma unroll
            for (int n = 0; n < 2; n++) {
                int d = wd0 + n * 16 + lr;
                size_t o = ((size_t)(b * NSEQ + q0 + ql)) * DMODEL + (size_t)h * DHEAD + d;
                if constexpr (LAYER == 0) res[qh][r][n] = resf[o];
                else                      res[qh][r][n] = (float)resb[o];
            }
        }
    }

    // ---- phase 0: pure loads (exp done in gemm epilogue; mask folded) ----
    const int k0 = lane * 8;
    const size_t sbase = (size_t)h * MROWS + b * NSEQ;
    float4 e0v = *reinterpret_cast<const float4*>(&ek_t[sbase + k0]);
    float4 e1v = *reinterpret_cast<const float4*>(&ek_t[sbase + k0 + 4]);
    float ek[8] = {e0v.x, e0v.y, e0v.z, e0v.w, e1v.x, e1v.y, e1v.z, e1v.w};
    float eq[8];
    #pragma unroll
    for (int g = 0; g < 8; g++)
        eq[g] = eq_t[sbase + q0 + wave * 8 + g];

    // ---- stage tile 0 into Vt[0] (waits only A-regs) ----
    WRITEV(A0, A1, A2, A3, 0);
    LOADS(A0, A1, A2, A3, 2);          // set A now carries tile 2

    // ---- phase 1: w[q][k] = exp(tanh) = e^{1-2z}, z = rcp(u+1), u = eq*ek ----
    #pragma unroll
    for (int g = 0; g < 8; g++) {
        int q = wave * 8 + g;
        float eqv = eq[g];
        bf16x8 wv;
        #pragma unroll
        for (int j = 0; j < 8; j++) {
            float u = eqv * ek[j];
            float z = __builtin_amdgcn_rcpf(u + 1.f);
            float p = __expf(fmaf(z, -2.f, 1.f));
            wv[j] = (__bf16)(u > 0.f ? p : 1.0f);   // masked: exp(-1e-8) ~= 1
        }
        *reinterpret_cast<bf16x8*>(&w[q][k0 ^ ((q & 7) << 3)]) = wv;   // swizzled store
    }
    BAR_LGKM();                        // flushes w + Vt[0]; globals stay in flight

    // ---- phase 2: PV via MFMA + ones-column row-sums; 1 barrier/tile ----
    bf16x8 vones;
    #pragma unroll
    for (int e = 0; e < 8; e++) vones[e] = (__bf16)1.0f;

    f32x4 acc[2][2] = {};
    f32x4 accs[2] = {};

    const int wswz = (lr & 7) << 3;    // per-lane w col swizzle

    #pragma unroll
    for (int t = 0; t < 8; t++) {
        const int buf = t & 1;
        const char* vtr = reinterpret_cast<const char*>(&Vt[buf][0]);
        __builtin_amdgcn_s_setprio(1);
        #pragma unroll
        for (int ks = 0; ks < 2; ks++) {
            int cb = (t * 64 + ks * 32 + lg * 8) ^ wswz;
            bf16x8 af0 = *reinterpret_cast<const bf16x8*>(&w[lr][cb]);
            bf16x8 af1 = *reinterpret_cast<const bf16x8*>(&w[16 + lr][cb]);
            #pragma unroll
            for (int n = 0; n < 2; n++) {
                int d    = wd0 + n * 16 + lr;
                int kbk  = ks * 4 + lg;
                int swzd = (d & 7) ^ ((d >> 3) & 7);
                bf16x8 bv = *reinterpret_cast<const bf16x8*>(vtr + d * 128 + ((kbk ^ swzd) << 4));
                acc[0][n] = __builtin_amdgcn_mfma_f32_16x16x32_bf16(af0, bv, acc[0][n], 0, 0, 0);
                acc[1][n] = __builtin_amdgcn_mfma_f32_16x16x32_bf16(af1, bv, acc[1][n], 0, 0, 0);
            }
            accs[0] = __builtin_amdgcn_mfma_f32_16x16x32_bf16(af0, vones, accs[0], 0, 0, 0);
            accs[1] = __builtin_amdgcn_mfma_f32_16x16x32_bf16(af1, vones, accs[1], 0, 0, 0);
        }
        __builtin_amdgcn_s_setprio(0);
        // stage next tile AFTER this tile's reads issued (lgkm pipe in-order)
        if (t < 7) {
            if ((t & 1) == 0) WRITEV(B0, B1, B2, B3, buf ^ 1);
            else              WRITEV(A0, A1, A2, A3, buf ^ 1);
        }
        if (t < 5) {
            if ((t & 1) == 0) LOADS(B0, B1, B2, B3, t + 3);
            else              LOADS(A0, A1, A2, A3, t + 3);
        }
        if (t < 7) BAR_LGKM();         // one barrier per tile (dbuf makes it safe)
    }

    // ---- epilogue: rden lane-local (from ones-MFMA), tanh, +residual ----
    #pragma unroll
    for (int qh = 0; qh < 2; qh++) {
        #pragma unroll
        for (int r = 0; r < 4; r++) {
            int ql = qh * 16 + lg * 4 + r;
            float rden = __builtin_amdgcn_rcpf(accs[qh][r]);
            #pragma unroll
            for (int n = 0; n < 2; n++) {
                int d  = wd0 + n * 16 + lr;
                float hv = acc[qh][n][r] * rden;
                float e2 = __expf(2.f * hv);
                float tv = 1.f - 2.f * __builtin_amdgcn_rcpf(e2 + 1.f);   // tanh(hv)
                size_t o = ((size_t)(b * NSEQ + q0 + ql)) * DMODEL + (size_t)h * DHEAD + d;
                float ov = res[qh][r][n] + tv;
                if constexpr (LAYER == 0) outb[o] = (__bf16)ov;
                else                      outf[o] = ov;
            }
        }
    }
    #undef LOADS
    #undef WRITEV
}

extern "C" void kernel_launch(void* const* d_in, const int* in_sizes, int n_in,
                              void* d_out, int out_size, void* d_ws, size_t ws_size,
                              hipStream_t stream) {
    const float* pmask   = (const float*)d_in[0];
    const float* feature = (const float*)d_in[1];
    const float* W       = (const float*)d_in[2];
    const float* Wa      = (const float*)d_in[3];
    float* out = (float*)d_out;
    char* ws = (char*)d_ws;

    __bf16* Abf  = (__bf16*)ws;
    __bf16* Wbf  = (__bf16*)(ws + 12582912);
    __bf16* QKbf = (__bf16*)(ws + 12582912 + 1179648);
    float*  eq   = (float*)(ws + 12582912 + 1179648 + 12582912);
    float*  ek   = eq + MROWS * NHEAD;

    const int wN4 = (DMODEL * DMODEL) / 4;      // 147,456

    // tiny cvt: W only (feature-cvt eliminated — gemm1 reads fp32 directly)
    hipLaunchKernelGGL(cvt_bf16_kernel, dim3((wN4 + 255) / 256), dim3(256), 0, stream,
                       W, Wbf, wN4);

    // ---- layer 1: gemm reads fp32 feature; attn residual fp32, out bf16 Abf ----
    hipLaunchKernelGGL((gemm_bt<true>), dim3(768), dim3(256), 0, stream,
                       (const void*)feature, Wbf, QKbf, Wa, pmask, eq, ek);
    hipLaunchKernelGGL((attn_pv<0>), dim3(1536), dim3(256), 0, stream,
                       QKbf, eq, ek, feature, (const __bf16*)nullptr,
                       (float*)nullptr, Abf);

    // ---- layer 2: gemm reads bf16 Abf; attn residual bf16 Abf, out fp32 ----
    hipLaunchKernelGGL((gemm_bt<false>), dim3(768), dim3(256), 0, stream,
                       (const void*)Abf, Wbf, QKbf, Wa, pmask, eq, ek);
    hipLaunchKernelGGL((attn_pv<1>), dim3(1536), dim3(256), 0, stream,
                       QKbf, eq, ek, (const float*)nullptr, Abf,
                       out, (__bf16*)nullptr);
}

// Round 15
// 98.952 us; speedup vs baseline: 1.0482x; 1.0482x over previous
//
#include <hip/hip_runtime.h>
#include <hip/hip_bf16.h>
#include <stdint.h>

// Problem constants (B=16, N=512, D=768, H=6, Dh=128, layers=2)
#define BATCH 16
#define NSEQ  512
#define DMODEL 768
#define NHEAD 6
#define DHEAD 128
#define MROWS (BATCH * NSEQ)   // 8192
#define QBLK  32
#define KTILE 64

typedef __attribute__((ext_vector_type(8))) __bf16 bf16x8;
typedef __attribute__((ext_vector_type(4))) __bf16 bf16x4;
typedef __attribute__((ext_vector_type(4))) float  f32x4;
typedef __attribute__((ext_vector_type(4))) unsigned int u32x4;

#define GLD16(gp, lp) __builtin_amdgcn_global_load_lds( \
    (const __attribute__((address_space(1))) unsigned int*)(gp), \
    (__attribute__((address_space(3))) unsigned int*)(lp), 16, 0, 0)

// raw barrier (does NOT drain vmcnt -> global loads stay in flight)
#define BAR_PLAIN() do { asm volatile("" ::: "memory"); \
    __builtin_amdgcn_s_barrier(); asm volatile("" ::: "memory"); } while (0)
// barrier with LDS-op flush (producer side of ds_write -> cross-wave read)
#define BAR_LGKM() do { asm volatile("s_waitcnt lgkmcnt(0)" ::: "memory"); \
    __builtin_amdgcn_s_barrier(); asm volatile("" ::: "memory"); } while (0)

// ---------------- fp32 -> bf16 conversion (W only; 0.6 MB) ---------------
__global__ void cvt_bf16_kernel(const float* __restrict__ src,
                                __bf16* __restrict__ dst, int n4) {
    int i = blockIdx.x * blockDim.x + threadIdx.x;
    if (i < n4) {
        float4 v = reinterpret_cast<const float4*>(src)[i];
        bf16x4 o;
        o.x = (__bf16)v.x; o.y = (__bf16)v.y; o.z = (__bf16)v.z; o.w = (__bf16)v.w;
        reinterpret_cast<bf16x4*>(dst)[i] = o;
    }
}

// ---------------- bf16 MFMA GEMM (64x128 tile) + fused eq/ek epilogue -----
// AFP32=true: A staged as fp32 via the SAME GLD16 pipeline, swizzled source,
// fp32->bf16 cvt at fragment read under MFMA shadow (R14 structure).
template<bool AFP32>
__global__ __launch_bounds__(256) void gemm_bt(const void* __restrict__ Av,
                                               const __bf16* __restrict__ Bm,
                                               __bf16* __restrict__ C,
                                               const float* __restrict__ Wa,
                                               const float* __restrict__ pmask,
                                               float* __restrict__ eq_t,
                                               float* __restrict__ ek_t) {
    const __bf16* Ab = reinterpret_cast<const __bf16*>(Av);
    const float*  Af = reinterpret_cast<const float*>(Av);

    __shared__ __align__(16) __bf16 As[2][AFP32 ? 4096 : 2048];
    __shared__ __align__(16) __bf16 Bs[2][128 * 32];
    const int tid  = threadIdx.x;
    const int lane = tid & 63;
    const int wave = tid >> 6;
    const int wm = wave >> 1, wn = wave & 1;   // wave: 32m x 64n

    const int wg  = blockIdx.x;
    const int nid = (wg & 7) * 96 + (wg >> 3);  // 768 = 8*96
    const int bx  = nid % 6;
    const int by  = nid / 6;
    const int m0 = by * 64;
    const int n0 = bx * 128;

    f32x4 acc[2][4] = {};

    const int e0   = tid * 8;
    const int row0 = tid >> 2;
    const int k0i  = (tid & 3) * 8;

    const int lr = lane & 15;
    const int lg = lane >> 4;
    const int kb = lg * 8;

    auto STAGE = [&](int kt, int bufi) {
        if constexpr (AFP32) {
            #pragma unroll
            for (int i2 = 0; i2 < 2; i2++) {
                int tt  = tid + 256 * i2;
                int row = tt >> 3;
                int k0s = ((tt & 7) * 4) ^ ((row & 7) << 2);
                GLD16(Af + (size_t)(m0 + row) * DMODEL + kt + k0s,
                      reinterpret_cast<float*>(&As[bufi][0]) + tt * 4);
            }
        } else {
            GLD16(Ab + (size_t)(m0 + row0) * DMODEL + kt + k0i, &As[bufi][e0]);
        }
        GLD16(Bm + (size_t)(n0 + row0)      * DMODEL + kt + k0i, &Bs[bufi][e0]);
        GLD16(Bm + (size_t)(n0 + row0 + 64) * DMODEL + kt + k0i, &Bs[bufi][e0 + 2048]);
    };

    STAGE(0, 0);

    for (int t = 0; t < 24; t++) {
        const int buf = t & 1;
        if (t < 23) {
            STAGE((t + 1) * 32, buf ^ 1);
            if constexpr (AFP32) asm volatile("s_waitcnt vmcnt(4)" ::: "memory");
            else                 asm volatile("s_waitcnt vmcnt(3)" ::: "memory");
        } else {
            asm volatile("s_waitcnt vmcnt(0)" ::: "memory");
        }
        __builtin_amdgcn_s_barrier();
        asm volatile("" ::: "memory");

        bf16x8 af[2], bfv[4];
        if constexpr (AFP32) {
            const float* A32 = reinterpret_cast<const float*>(&As[buf][0]);
            const int sw = (lr & 7) << 2;
            #pragma unroll
            for (int i = 0; i < 2; i++) {
                int row = wm * 32 + i * 16 + lr;
                f32x4 lo = *reinterpret_cast<const f32x4*>(&A32[row * 32 + (kb ^ sw)]);
                f32x4 hi = *reinterpret_cast<const f32x4*>(&A32[row * 32 + ((kb + 4) ^ sw)]);
                #pragma unroll
                for (int j = 0; j < 4; j++) {
                    af[i][j]     = (__bf16)lo[j];
                    af[i][4 + j] = (__bf16)hi[j];
                }
            }
        } else {
            #pragma unroll
            for (int i = 0; i < 2; i++)
                af[i] = *reinterpret_cast<const bf16x8*>(&As[buf][(wm * 32 + i * 16 + lr) * 32 + kb]);
        }
        #pragma unroll
        for (int j = 0; j < 4; j++)
            bfv[j] = *reinterpret_cast<const bf16x8*>(&Bs[buf][(wn * 64 + j * 16 + lr) * 32 + kb]);
        #pragma unroll
        for (int i = 0; i < 2; i++)
            #pragma unroll
            for (int j = 0; j < 4; j++)
                acc[i][j] = __builtin_amdgcn_mfma_f32_16x16x32_bf16(af[i], bfv[j], acc[i][j], 0, 0, 0);

        BAR_PLAIN();
    }

    const int rg = lg * 4;
    #pragma unroll
    for (int i = 0; i < 2; i++) {
        #pragma unroll
        for (int j = 0; j < 4; j++) {
            #pragma unroll
            for (int r = 0; r < 4; r++) {
                int row = m0 + wm * 32 + i * 16 + rg + r;
                int col = n0 + wn * 64 + j * 16 + lr;
                C[(size_t)row * DMODEL + col] = (__bf16)acc[i][j][r];
            }
        }
    }

    // ---- fused sq/sk reduction -> eq = pm*e^{2sq}, ek = pm*e^{2sk} ----
    const int h = bx;
    float wqv[4], wkv[4];
    #pragma unroll
    for (int j = 0; j < 4; j++) {
        int d = wn * 64 + j * 16 + lr;
        wqv[j] = Wa[h * 256 + d];
        wkv[j] = Wa[h * 256 + 128 + d];
    }
    float* red = reinterpret_cast<float*>(&As[0][0]);
    #pragma unroll
    for (int i = 0; i < 2; i++) {
        #pragma unroll
        for (int r = 0; r < 4; r++) {
            float aq = 0.f, ak = 0.f;
            #pragma unroll
            for (int j = 0; j < 4; j++) {
                aq += acc[i][j][r] * wqv[j];
                ak += acc[i][j][r] * wkv[j];
            }
            #pragma unroll
            for (int off = 1; off < 16; off <<= 1) {
                aq += __shfl_xor(aq, off);
                ak += __shfl_xor(ak, off);
            }
            if (lr == 0) {
                int row = wm * 32 + i * 16 + rg + r;
                red[(0 * 64 + row) * 2 + wn] = aq;
                red[(1 * 64 + row) * 2 + wn] = ak;
            }
        }
    }
    __syncthreads();
    if (tid < 64) {
        int row = m0 + tid;
        float s = red[tid * 2] + red[tid * 2 + 1];
        eq_t[(size_t)h * MROWS + row] = (pmask[row] > 0.f) ? __expf(2.f * s) : 0.f;
    } else if (tid < 128) {
        int rl  = tid - 64;
        int row = m0 + rl;
        float s = red[(64 + rl) * 2] + red[(64 + rl) * 2 + 1];
        ek_t[(size_t)h * MROWS + row] = (pmask[row] > 0.f) ? __expf(2.f * s) : 0.f;
    }
}

// ---------------- fused score/softmax/MFMA-PV/tanh/residual ----------------
// grid 1536 XCD-chunked; block 256 (4 waves x 32 d-cols). QBLK=32.
// WAVE-PRIVATE Vt: each wave stages its own 32-d slice of V (lane: kg=lane>>2
// k-rows, dg=lane&3 d-cols) -> PV loop is BARRIER-FREE (intra-wave in-order
// lgkm pipe + wave-local lgkmcnt(0) replaces 7 block barriers). Single-buffer
// Vt (reads precede writes in pipe order). LDS = 32KB w + 16KB Vt = 48KB.
template<int LAYER>
__global__ __launch_bounds__(256) void attn_pv(const __bf16* __restrict__ QK,
                                               const float* __restrict__ eq_t,
                                               const float* __restrict__ ek_t,
                                               const float* __restrict__ resf,
                                               const __bf16* __restrict__ resb,
                                               float* __restrict__ outf,
                                               __bf16* __restrict__ outb) {
    const int wg  = blockIdx.x;
    const int nid = (wg & 7) * 192 + (wg >> 3);   // bijective: 1536 = 8*192
    const int qt = nid & 15;          // 16 q-tiles of 32
    const int hb = nid >> 4;          // 0..95
    const int h  = hb % NHEAD;
    const int b  = hb / NHEAD;
    const int q0 = qt * QBLK;

    __shared__ __align__(16) __bf16 w[QBLK][512];        // 32,768 B (swizzled cols)
    __shared__ __align__(16) __bf16 Vt[4][32 * KTILE];   // 16,384 B, wave-private slices
    const int tid  = threadIdx.x;
    const int lane = tid & 63;
    const int wave = tid >> 6;

    const int wd0 = wave * 32;
    const int lr  = lane & 15;
    const int lg  = lane >> 4;

    // ---- wave-private staging geometry; issue V tiles 0,1 EARLY ----
    const int kg = lane >> 2;         // 0..15 -> k rows kg*4..+3
    const int dg = lane & 3;          // 0..3  -> d cols wd0 + dg*8..+7
    const __bf16* Vbase = QK + (size_t)b * NSEQ * DMODEL + (size_t)h * DHEAD + wd0 + dg * 8;
    char* vtw = reinterpret_cast<char*>(&Vt[0][0]) + wave * 4096;

    u32x4 A0, A1, A2, A3, B0, B1, B2, B3;
    #define LOADS(S0, S1, S2, S3, t) do { \
        const __bf16* p = Vbase + (size_t)((t) * KTILE + kg * 4) * DMODEL; \
        S0 = *reinterpret_cast<const u32x4*>(p); \
        S1 = *reinterpret_cast<const u32x4*>(p + DMODEL); \
        S2 = *reinterpret_cast<const u32x4*>(p + 2 * DMODEL); \
        S3 = *reinterpret_cast<const u32x4*>(p + 3 * DMODEL); \
    } while (0)
    // pack 4 k per d via v_perm; Vt_w[d_local][k'], k' = k ^ (8*swz(d_local)),
    // swz(dl) = (dl&7)^((dl>>3)&7) = j^dg here. b64 writes: exactly 4/slot (floor).
    #define WRITEV(S0, S1, S2, S3) do { \
        _Pragma("unroll") \
        for (int j = 0; j < 8; j++) { \
            int dl = dg * 8 + j; \
            int sw = j ^ dg; \
            unsigned sel = (j & 1) ? 0x07060302u : 0x05040100u; \
            unsigned lo = __builtin_amdgcn_perm(S1[j >> 1], S0[j >> 1], sel); \
            unsigned hi = __builtin_amdgcn_perm(S3[j >> 1], S2[j >> 1], sel); \
            unsigned long long pk = (unsigned long long)lo | ((unsigned long long)hi << 32); \
            *reinterpret_cast<unsigned long long*>(vtw + dl * 128 + (((kg * 4) ^ (sw << 3)) * 2)) = pk; \
        } \
    } while (0)

    LOADS(A0, A1, A2, A3, 0);          // latency hidden under phase 0/1
    LOADS(B0, B1, B2, B3, 1);

    // ---- early residual prefetch (compile-time source select) ----
    float res[2][4][2];
    #pragma unroll
    for (int qh = 0; qh < 2; qh++) {
        #pragma unroll
        for (int r = 0; r < 4; r++) {
            int ql = qh * 16 + lg * 4 + r;
            #pragma unroll
            for (int n = 0; n < 2; n++) {
                int d = wd0 + n * 16 + lr;
                size_t o = ((size_t)(b * NSEQ + q0 + ql)) * DMODEL + (size_t)h * DHEAD + d;
                if constexpr (LAYER == 0) res[qh][r][n] = resf[o];
                else                      res[qh][r][n] = (float)resb[o];
            }
        }
    }

    // ---- phase 0: pure loads (exp done in gemm epilogue; mask folded) ----
    const int k0 = lane * 8;
    const size_t sbase = (size_t)h * MROWS + b * NSEQ;
    float4 e0v = *reinterpret_cast<const float4*>(&ek_t[sbase + k0]);
    float4 e1v = *reinterpret_cast<const float4*>(&ek_t[sbase + k0 + 4]);
    float ek[8] = {e0v.x, e0v.y, e0v.z, e0v.w, e1v.x, e1v.y, e1v.z, e1v.w};
    float eq[8];
    #pragma unroll
    for (int g = 0; g < 8; g++)
        eq[g] = eq_t[sbase + q0 + wave * 8 + g];

    // ---- stage tile 0 into own Vt slice (no barrier needed: wave-private) ----
    WRITEV(A0, A1, A2, A3);
    LOADS(A0, A1, A2, A3, 2);          // set A now carries tile 2

    // ---- phase 1: w[q][k] = exp(tanh) = e^{1-2z}, z = rcp(u+1), u = eq*ek ----
    #pragma unroll
    for (int g = 0; g < 8; g++) {
        int q = wave * 8 + g;
        float eqv = eq[g];
        bf16x8 wv;
        #pragma unroll
        for (int j = 0; j < 8; j++) {
            float u = eqv * ek[j];
            float z = __builtin_amdgcn_rcpf(u + 1.f);
            float p = __expf(fmaf(z, -2.f, 1.f));
            wv[j] = (__bf16)(u > 0.f ? p : 1.0f);   // masked: exp(-1e-8) ~= 1
        }
        *reinterpret_cast<bf16x8*>(&w[q][k0 ^ ((q & 7) << 3)]) = wv;   // swizzled store
    }
    BAR_LGKM();                        // the ONLY block barrier: w visible

    // ---- phase 2: BARRIER-FREE PV loop (wave-private Vt, in-order lgkm) ----
    bf16x8 vones;
    #pragma unroll
    for (int e = 0; e < 8; e++) vones[e] = (__bf16)1.0f;

    f32x4 acc[2][2] = {};
    f32x4 accs[2] = {};

    const int wswz = (lr & 7) << 3;    // per-lane w col swizzle

    #pragma unroll
    for (int t = 0; t < 8; t++) {
        __builtin_amdgcn_s_setprio(1);
        #pragma unroll
        for (int ks = 0; ks < 2; ks++) {
            int cb = (t * 64 + ks * 32 + lg * 8) ^ wswz;
            bf16x8 af0 = *reinterpret_cast<const bf16x8*>(&w[lr][cb]);
            bf16x8 af1 = *reinterpret_cast<const bf16x8*>(&w[16 + lr][cb]);
            #pragma unroll
            for (int n = 0; n < 2; n++) {
                int dl   = n * 16 + lr;
                int sw   = (dl & 7) ^ ((dl >> 3) & 7);
                bf16x8 bv = *reinterpret_cast<const bf16x8*>(
                    vtw + dl * 128 + (((ks * 4 + lg) ^ sw) << 4));
                acc[0][n] = __builtin_amdgcn_mfma_f32_16x16x32_bf16(af0, bv, acc[0][n], 0, 0, 0);
                acc[1][n] = __builtin_amdgcn_mfma_f32_16x16x32_bf16(af1, bv, acc[1][n], 0, 0, 0);
            }
            accs[0] = __builtin_amdgcn_mfma_f32_16x16x32_bf16(af0, vones, accs[0], 0, 0, 0);
            accs[1] = __builtin_amdgcn_mfma_f32_16x16x32_bf16(af1, vones, accs[1], 0, 0, 0);
        }
        __builtin_amdgcn_s_setprio(0);
        if (t < 7) {
            // pin order: all reads of tile t above; then wave-local drain;
            // then single-buffer overwrite with tile t+1 (no block barrier).
            __builtin_amdgcn_sched_barrier(0);
            asm volatile("s_waitcnt lgkmcnt(0)" ::: "memory");
            if ((t & 1) == 0) WRITEV(B0, B1, B2, B3);
            else              WRITEV(A0, A1, A2, A3);
        }
        if (t < 5) {
            if ((t & 1) == 0) LOADS(B0, B1, B2, B3, t + 3);
            else              LOADS(A0, A1, A2, A3, t + 3);
        }
    }

    // ---- epilogue: rden lane-local (from ones-MFMA), tanh, +residual ----
    #pragma unroll
    for (int qh = 0; qh < 2; qh++) {
        #pragma unroll
        for (int r = 0; r < 4; r++) {
            int ql = qh * 16 + lg * 4 + r;
            float rden = __builtin_amdgcn_rcpf(accs[qh][r]);
            #pragma unroll
            for (int n = 0; n < 2; n++) {
                int d  = wd0 + n * 16 + lr;
                float hv = acc[qh][n][r] * rden;
                float e2 = __expf(2.f * hv);
                float tv = 1.f - 2.f * __builtin_amdgcn_rcpf(e2 + 1.f);   // tanh(hv)
                size_t o = ((size_t)(b * NSEQ + q0 + ql)) * DMODEL + (size_t)h * DHEAD + d;
                float ov = res[qh][r][n] + tv;
                if constexpr (LAYER == 0) outb[o] = (__bf16)ov;
                else                      outf[o] = ov;
            }
        }
    }
    #undef LOADS
    #undef WRITEV
}

extern "C" void kernel_launch(void* const* d_in, const int* in_sizes, int n_in,
                              void* d_out, int out_size, void* d_ws, size_t ws_size,
                              hipStream_t stream) {
    const float* pmask   = (const float*)d_in[0];
    const float* feature = (const float*)d_in[1];
    const float* W       = (const float*)d_in[2];
    const float* Wa      = (const float*)d_in[3];
    float* out = (float*)d_out;
    char* ws = (char*)d_ws;

    __bf16* Abf  = (__bf16*)ws;
    __bf16* Wbf  = (__bf16*)(ws + 12582912);
    __bf16* QKbf = (__bf16*)(ws + 12582912 + 1179648);
    float*  eq   = (float*)(ws + 12582912 + 1179648 + 12582912);
    float*  ek   = eq + MROWS * NHEAD;

    const int wN4 = (DMODEL * DMODEL) / 4;      // 147,456

    // tiny cvt: W only (gemm1 reads fp32 feature directly)
    hipLaunchKernelGGL(cvt_bf16_kernel, dim3((wN4 + 255) / 256), dim3(256), 0, stream,
                       W, Wbf, wN4);

    // ---- layer 1: gemm reads fp32 feature; attn residual fp32, out bf16 Abf ----
    hipLaunchKernelGGL((gemm_bt<true>), dim3(768), dim3(256), 0, stream,
                       (const void*)feature, Wbf, QKbf, Wa, pmask, eq, ek);
    hipLaunchKernelGGL((attn_pv<0>), dim3(1536), dim3(256), 0, stream,
                       QKbf, eq, ek, feature, (const __bf16*)nullptr,
                       (float*)nullptr, Abf);

    // ---- layer 2: gemm reads bf16 Abf; attn residual bf16 Abf, out fp32 ----
    hipLaunchKernelGGL((gemm_bt<false>), dim3(768), dim3(256), 0, stream,
                       (const void*)Abf, Wbf, QKbf, Wa, pmask, eq, ek);
    hipLaunchKernelGGL((attn_pv<1>), dim3(1536), dim3(256), 0, stream,
                       QKbf, eq, ek, (const float*)nullptr, Abf,
                       out, (__bf16*)nullptr);
}